// Round 8
// baseline (38.917 us; speedup 1.0000x reference)
//
#include <hip/hip_runtime.h>
#include <math.h>

#define N_RAYS 86400
#define N_SAMP 287
#define GRP_W  16          // lanes per ray (4 rays per wave)
#define N_CHUNK 18         // ceil(287/16)
#define LOG2E 1.4426950408889634f

// DPP row_shr:N prefix-shift within the 16-lane row; lanes below the row edge
// read `old` = 1.0f (multiplicative identity).
#define ROW_SHR_OLD1(x, N)                                                   \
    __int_as_float(__builtin_amdgcn_update_dpp(                              \
        0x3f800000 /*1.0f*/, __float_as_int(x), 0x110 | (N), 0xF, 0xF, false))

// ds_swizzle BitMode: new_lane = ((lane & and) | or) ^ xor  (per 32-lane half)
#define SWZ(x, pat) __int_as_float(__builtin_amdgcn_ds_swizzle(__float_as_int(x), (pat)))
#define SWZ_BCAST15 0x1F0   // lane 15 of each 16-group
#define SWZ_XOR(m)  (((m) << 10) | 0x1F)

struct F2 { float lo, hi; };

// Conservative chunk count from the slab exit bound (origin strictly inside).
// The per-sample strict-compare mask remains authoritative; this only bounds
// the loop. +2-sample guard >> fp error (~3e-4 samples).
__device__ __forceinline__ int ray_nch(float ox, float oy, float oz,
                                       float dx, float dy, float dz,
                                       float stepf) {
    float invx = 1.0f / __fmul_rn(dx, stepf);
    float invy = 1.0f / __fmul_rn(dy, stepf);
    float invz = 1.0f / __fmul_rn(dz, stepf);
    float tx = fmaxf((40.0f - ox) * invx, (-40.0f - ox) * invx);
    float ty = fmaxf((40.0f - oy) * invy, (-40.0f - oy) * invy);
    float tz = fmaxf((5.4f - oz) * invz, (-1.0f - oz) * invz);
    float te = fminf(fminf(fminf(tx, ty), tz), 300.0f);
    int s_stop = min((int)te + 2, N_SAMP);
    return (s_stop + GRP_W - 1) >> 4;      // 1..18
}

// k1: per-ray chunk count + histogram (bucket b = N_CHUNK - nch, descending)
__global__ __launch_bounds__(256) void k_len(
    const float* __restrict__ ro, const float* __restrict__ rd,
    int* __restrict__ nch_arr, int* __restrict__ hist, float stepf)
{
    __shared__ int lh[N_CHUNK];
    if (threadIdx.x < N_CHUNK) lh[threadIdx.x] = 0;
    __syncthreads();
    int t = blockIdx.x * 256 + threadIdx.x;
    if (t < N_RAYS) {
        int nch = ray_nch(ro[3*t], ro[3*t+1], ro[3*t+2],
                          rd[3*t], rd[3*t+1], rd[3*t+2], stepf);
        nch_arr[t] = nch;
        atomicAdd(&lh[N_CHUNK - nch], 1);
    }
    __syncthreads();
    if (threadIdx.x < N_CHUNK && lh[threadIdx.x])
        atomicAdd(&hist[threadIdx.x], lh[threadIdx.x]);
}

// k2: bucket scatter -> sorted[slot] = ray | nch<<20  (descending nch order)
__global__ __launch_bounds__(256) void k_scatter(
    const int* __restrict__ nch_arr, const int* __restrict__ hist,
    int* __restrict__ cursor, unsigned* __restrict__ sorted)
{
    __shared__ int lcount[N_CHUNK], lbase[N_CHUNK];
    if (threadIdx.x < N_CHUNK) lcount[threadIdx.x] = 0;
    __syncthreads();
    int t = blockIdx.x * 256 + threadIdx.x;
    int b = 0, rank = 0, nch = 0;
    if (t < N_RAYS) {
        nch = nch_arr[t];
        b = N_CHUNK - nch;
        rank = atomicAdd(&lcount[b], 1);
    }
    __syncthreads();
    if (threadIdx.x < N_CHUNK && lcount[threadIdx.x])
        lbase[threadIdx.x] = atomicAdd(&cursor[threadIdx.x], lcount[threadIdx.x]);
    __syncthreads();
    if (t < N_RAYS) {
        int off = 0;
        #pragma unroll
        for (int i = 0; i < N_CHUNK; ++i) off += (i < b) ? hist[i] : 0;
        sorted[off + lbase[b] + rank] = (unsigned)t | ((unsigned)nch << 20);
    }
}

// k3: main march; group g handles ray sorted[g] (groups in a wave have
// near-equal chunk counts after the sort)
__global__ __launch_bounds__(256) void nerf_depth_kernel(
    const float* __restrict__ rays_o,
    const float* __restrict__ rays_d,
    const float* __restrict__ voxel,
    const unsigned* __restrict__ sorted,
    float* __restrict__ depth_out,
    float stepf, float delta)
{
    const int lane = threadIdx.x & 63;
    const int sub  = lane & (GRP_W - 1);
    const int g    = (blockIdx.x * blockDim.x + threadIdx.x) >> 4;

    const unsigned e = sorted[g];
    const int ray = e & 0xFFFFF;
    const int nch = e >> 20;

    const float ox = rays_o[3*ray+0], oy = rays_o[3*ray+1], oz = rays_o[3*ray+2];
    const float dx = rays_d[3*ray+0], dy = rays_d[3*ray+1], dz = rays_d[3*ray+2];

    const float cx1 = 199.0f / 80.0f;                  const float cx0 = 40.0f * cx1;
    const float cz1 = 15.0f / (5.4f - (-1.0f));        const float cz0 = 1.0f * cz1;
    const float negdelta = -delta;

    float T = 1.0f;
    float depth_acc = 0.0f;
    bool  dead = false;        // group-uniform

    int c = 0;
    while (true) {
        const int  s     = c * GRP_W + sub;
        const bool valid = (s < N_SAMP);
        const float z  = __fmul_rn(stepf, (float)s);
        // bit-exact vs numpy: separate mul + add, strict compares
        const float px = __fadd_rn(ox, __fmul_rn(dx, z));
        const float py = __fadd_rn(oy, __fmul_rn(dy, z));
        const float pz = __fadd_rn(oz, __fmul_rn(dz, z));
        const bool inside = !((fmaxf(fabsf(px), fabsf(py)) > 40.0f) |
                              (pz < -1.0f) | (pz > 5.4f));
        const bool inb = inside && valid && !dead;

        float alpha = 0.0f, az = 0.0f;
        if (inb) {
            float ix = fminf(fmaxf(__builtin_fmaf(px, cx1, cx0), 0.0f), 199.0f);
            float iy = fminf(fmaxf(__builtin_fmaf(py, cx1, cx0), 0.0f), 199.0f);
            float iz = fminf(fmaxf(__builtin_fmaf(pz, cz1, cz0), 0.0f), 15.0f);
            int x0 = min((int)ix, 198);
            int y0 = min((int)iy, 198);
            int z0 = min((int)iz, 14);
            float fx = ix - (float)x0;
            float fy = iy - (float)y0;
            float fz = iz - (float)z0;
            const float* p00 = voxel + ((x0 * 200 + y0) * 16 + z0);
            F2 q00, q01, q10, q11;
            __builtin_memcpy(&q00, p00,        8);
            __builtin_memcpy(&q01, p00 + 16,   8);
            __builtin_memcpy(&q10, p00 + 3200, 8);
            __builtin_memcpy(&q11, p00 + 3216, 8);
            float c00 = q00.lo + fz * (q00.hi - q00.lo);
            float c01 = q01.lo + fz * (q01.hi - q01.lo);
            float c10 = q10.lo + fz * (q10.hi - q10.lo);
            float c11 = q11.lo + fz * (q11.hi - q11.lo);
            float c0  = c00 + fy * (c01 - c00);
            float c1  = c10 + fy * (c11 - c10);
            float d   = c0  + fx * (c1  - c0);
            float e2 = exp2f(d * LOG2E);
            float lg = __log2f(1.0f + e2);
            alpha = 1.0f - exp2f(negdelta * lg);
            az = alpha * z;
        }

        float gg = fmaxf(1.0f - alpha, 1e-10f);

        float P = gg;
        P *= ROW_SHR_OLD1(P, 1);
        P *= ROW_SHR_OLD1(P, 2);
        P *= ROW_SHR_OLD1(P, 4);
        P *= ROW_SHR_OLD1(P, 8);
        float E = ROW_SHR_OLD1(P, 1);      // exclusive prefix (lane0 -> 1.0)

        depth_acc = __builtin_fmaf(az, T * E, depth_acc);
        T *= SWZ(P, SWZ_BCAST15);

        ++c;
        // own chunks exhausted, or transmittance dead (residual <= 1e-6*57.4)
        dead = dead | (c >= nch) | (T < 1e-6f);
        if (__all(dead)) break;
    }

    depth_acc += SWZ(depth_acc, SWZ_XOR(1));
    depth_acc += SWZ(depth_acc, SWZ_XOR(2));
    depth_acc += SWZ(depth_acc, SWZ_XOR(4));
    depth_acc += SWZ(depth_acc, SWZ_XOR(8));
    if (sub == 0) depth_out[ray] = depth_acc;
}

extern "C" void kernel_launch(void* const* d_in, const int* in_sizes, int n_in,
                              void* d_out, int out_size, void* d_ws, size_t ws_size,
                              hipStream_t stream) {
    (void)in_sizes; (void)n_in; (void)ws_size; (void)out_size;
    const float* rays_o = (const float*)d_in[0];
    const float* rays_d = (const float*)d_in[1];
    const float* voxel  = (const float*)d_in[2];
    float* out = (float*)d_out;

    int*      hist    = (int*)d_ws;                 // 18 ints
    int*      cursor  = (int*)d_ws + 32;            // 18 ints
    int*      nch_arr = (int*)d_ws + 1024;          // 86400 ints
    unsigned* sorted  = (unsigned*)((int*)d_ws + 1024 + N_RAYS);

    // numpy constant chain in float32: step == 0.2f
    float rngz  = 5.4f - (-1.0f);
    float prod  = (80.0f * 80.0f) * rngz;
    float ratio = prod / 640000.0f;
    float stepf = (float)(0.5 * pow((double)ratio, 1.0 / 3.0));
    float delta = stepf * 286.0f - stepf * 285.0f;

    hipMemsetAsync(d_ws, 0, 256, stream);           // zero hist + cursor
    const int pb = (N_RAYS + 255) / 256;            // 338 blocks
    k_len    <<<pb, 256, 0, stream>>>(rays_o, rays_d, nch_arr, hist, stepf);
    k_scatter<<<pb, 256, 0, stream>>>(nch_arr, hist, cursor, sorted);
    nerf_depth_kernel<<<N_RAYS / 16, 256, 0, stream>>>(rays_o, rays_d, voxel,
                                                       sorted, out, stepf, delta);
}

// Round 9
// 34.725 us; speedup vs baseline: 1.1207x; 1.1207x over previous
//
#include <hip/hip_runtime.h>
#include <math.h>

#define N_RAYS 86400
#define N_SAMP 287
#define GRP_W  16          // lanes per ray (4 rays per wave)
#define N_CHUNK 18         // ceil(287/16)
#define LOG2E 1.4426950408889634f

// --- DPP cross-lane helpers (16-lane rows, pure VALU, no LDS pipe) ---
#define DPP(x, ctrl) __int_as_float(__builtin_amdgcn_update_dpp(             \
        0, __float_as_int(x), (ctrl), 0xF, 0xF, false))
// row_shr:N, lanes shifted past the row edge read old = 1.0f (mul identity)
#define ROW_SHR_OLD1(x, N) __int_as_float(__builtin_amdgcn_update_dpp(       \
        0x3f800000, __float_as_int(x), 0x110 | (N), 0xF, 0xF, false))
#define QPERM_X1 0xB1   // quad_perm [1,0,3,2]  (lane ^= 1)
#define QPERM_X2 0x4E   // quad_perm [2,3,0,1]  (lane ^= 2)
#define ROW_ROR4 0x124  // rotate within 16-row by 4
#define ROW_ROR8 0x128  // rotate within 16-row by 8

struct F2 { float lo, hi; };   // 8-byte z-pair

__global__ __launch_bounds__(256) void nerf_depth_kernel(
    const float* __restrict__ rays_o,
    const float* __restrict__ rays_d,
    const float* __restrict__ voxel,
    float* __restrict__ depth_out,
    float stepf, float delta)
{
    const int lane = threadIdx.x & 63;
    const int sub  = lane & (GRP_W - 1);
    const int grp  = lane >> 4;
    const int wave = (blockIdx.x * blockDim.x + threadIdx.x) >> 6;
    const int ray  = wave * 4 + grp;         // 86400 = 4 * 21600, exact

    const float ox = rays_o[3*ray+0], oy = rays_o[3*ray+1], oz = rays_o[3*ray+2];
    const float dx = rays_d[3*ray+0], dy = rays_d[3*ray+1], dz = rays_d[3*ray+2];

    const float cx1 = 199.0f / 80.0f;              const float cx0 = 40.0f * cx1;
    const float cz1 = 15.0f / (5.4f - (-1.0f));    const float cz0 = 1.0f * cz1;
    const float negdelta = -delta;

    // Conservative per-ray chunk bound via slab exit (origin strictly inside;
    // box convex => inside set along ray is a prefix). The per-sample
    // strict-compare mask below stays authoritative for VALUES; this only
    // bounds the loop. +2-sample guard >> fp error.
    int nch;
    {
        float ivx = 1.0f / __fmul_rn(dx, stepf);
        float ivy = 1.0f / __fmul_rn(dy, stepf);
        float ivz = 1.0f / __fmul_rn(dz, stepf);
        float tx = fmaxf((40.0f - ox) * ivx, (-40.0f - ox) * ivx);
        float ty = fmaxf((40.0f - oy) * ivy, (-40.0f - oy) * ivy);
        float tz = fmaxf((5.4f - oz) * ivz, (-1.0f - oz) * ivz);
        float te = fminf(fminf(fminf(tx, ty), tz), 300.0f);
        int s_stop = min((int)te + 2, N_SAMP);
        nch = (s_stop + GRP_W - 1) >> 4;     // 1..18
    }

    float U   = 1.0f;   // transmittance at current chunk entry (group-uniform)
    float acc = 0.0f;   // per-lane sum of T_{s+1} over own samples
    int   C   = 0;      // executed chunks

    for (int c = 0; c < N_CHUNK; ++c) {
        const int   s  = c * GRP_W + sub;
        const float z  = __fmul_rn(stepf, (float)s);
        // bit-exact vs numpy: separate mul + add, strict compares
        const float px = __fadd_rn(ox, __fmul_rn(dx, z));
        const float py = __fadd_rn(oy, __fmul_rn(dy, z));
        const float pz = __fadd_rn(oz, __fmul_rn(dz, z));
        const bool inb = !((fmaxf(fabsf(px), fabsf(py)) > 40.0f) |
                           (pz < -1.0f) | (pz > 5.4f)) && (s < N_SAMP);

        float ix = fminf(fmaxf(__builtin_fmaf(px, cx1, cx0), 0.0f), 199.0f);
        float iy = fminf(fmaxf(__builtin_fmaf(py, cx1, cx0), 0.0f), 199.0f);
        float iz = fminf(fmaxf(__builtin_fmaf(pz, cz1, cz0), 0.0f), 15.0f);
        int x0 = min((int)ix, 198);
        int y0 = min((int)iy, 198);
        int z0 = min((int)iz, 14);
        float fx = ix - (float)x0;
        float fy = iy - (float)y0;
        float fz = iz - (float)z0;
        const float* p00 = voxel + ((x0 * 200 + y0) * 16 + z0);
        F2 q00, q01, q10, q11;
        __builtin_memcpy(&q00, p00,        8);   // (x0,  y0  ) z-pair
        __builtin_memcpy(&q01, p00 + 16,   8);   // (x0,  y0+1)
        __builtin_memcpy(&q10, p00 + 3200, 8);   // (x0+1,y0  )
        __builtin_memcpy(&q11, p00 + 3216, 8);   // (x0+1,y0+1)
        float c00 = q00.lo + fz * (q00.hi - q00.lo);
        float c01 = q01.lo + fz * (q01.hi - q01.lo);
        float c10 = q10.lo + fz * (q10.hi - q10.lo);
        float c11 = q11.lo + fz * (q11.hi - q11.lo);
        float c0  = c00 + fy * (c01 - c00);
        float c1  = c10 + fy * (c11 - c10);
        float d   = c0  + fx * (c1  - c0);

        // g = 1 - alpha = exp(-delta*softplus(d)) = 2^(-delta*log2(1+e^d));
        // 1e-10 clip never binds (|d| <~ 6 => g >= ~0.3)
        float e2 = exp2f(d * LOG2E);
        float lg = __log2f(1.0f + e2);
        float g  = exp2f(negdelta * lg);
        g = inb ? g : 1.0f;

        // inclusive prefix product P_i = g_0*...*g_i  (4 DPP muls)
        float P = g;
        P *= ROW_SHR_OLD1(P, 1);
        P *= ROW_SHR_OLD1(P, 2);
        P *= ROW_SHR_OLD1(P, 4);
        P *= ROW_SHR_OLD1(P, 8);
        // full 16-product rho to ALL lanes (4 DPP muls; order differs per lane
        // by ~ulp only — harmless)
        float rho = g;
        rho *= DPP(rho, QPERM_X1);
        rho *= DPP(rho, QPERM_X2);
        rho *= DPP(rho, ROW_ROR4);
        rho *= DPP(rho, ROW_ROR8);

        acc = __builtin_fmaf(U, P, acc);   // accumulates T_{16c+i+1}
        U *= rho;
        C = c + 1;

        // own chunks exhausted or transmittance dead (residual <= ~1e-4)
        const bool dead = (U < 1e-6f) | (C >= nch);
        if (__all(dead)) break;
    }

    // telescoped cumsum: depth = step * (sum_{t=1}^{16C} T_t - 16*C*T_end)
    float asum = acc;
    asum += DPP(asum, QPERM_X1);
    asum += DPP(asum, QPERM_X2);
    asum += DPP(asum, ROW_ROR4);
    asum += DPP(asum, ROW_ROR8);
    if (sub == 0)
        depth_out[ray] = stepf * (asum - (float)(GRP_W * C) * U);
}

extern "C" void kernel_launch(void* const* d_in, const int* in_sizes, int n_in,
                              void* d_out, int out_size, void* d_ws, size_t ws_size,
                              hipStream_t stream) {
    (void)in_sizes; (void)n_in; (void)d_ws; (void)ws_size; (void)out_size;
    const float* rays_o = (const float*)d_in[0];
    const float* rays_d = (const float*)d_in[1];
    const float* voxel  = (const float*)d_in[2];
    float* out = (float*)d_out;

    // numpy constant chain in float32: step == 0.2f
    float rngz  = 5.4f - (-1.0f);
    float prod  = (80.0f * 80.0f) * rngz;
    float ratio = prod / 640000.0f;
    float stepf = (float)(0.5 * pow((double)ratio, 1.0 / 3.0));
    float delta = stepf * 286.0f - stepf * 285.0f;

    // 4 rays/wave, 4 waves/block => 16 rays/block; 86400/16 = 5400 blocks
    nerf_depth_kernel<<<N_RAYS / 16, 256, 0, stream>>>(rays_o, rays_d, voxel,
                                                       out, stepf, delta);
}

// Round 10
// 32.624 us; speedup vs baseline: 1.1929x; 1.0644x over previous
//
#include <hip/hip_runtime.h>
#include <hip/hip_fp16.h>
#include <math.h>

#define N_RAYS 86400
#define N_SAMP 287
#define GRP_W  16          // lanes per ray (4 rays per wave)
#define N_CHUNK 18         // ceil(287/16)
#define LOG2E 1.4426950408889634f
#define N_CELLS (200 * 200 * 16)

// DPP row_shr:N prefix-shift within the 16-lane row; lanes below the row edge
// read `old` = 1.0f (multiplicative identity).
#define ROW_SHR_OLD1(x, N)                                                   \
    __int_as_float(__builtin_amdgcn_update_dpp(                              \
        0x3f800000 /*1.0f*/, __float_as_int(x), 0x110 | (N), 0xF, 0xF, false))

// ds_swizzle BitMode: new_lane = ((lane & and) | or) ^ xor  (per 32-lane half)
#define SWZ(x, pat) __int_as_float(__builtin_amdgcn_ds_swizzle(__float_as_int(x), (pat)))
#define SWZ_BCAST15 0x1F0   // lane 15 of each 16-group
#define SWZ_XOR(m)  (((m) << 10) | 0x1F)

// Prepass: zp[cell(x,y,z)] = half2( v(x,y,z), v(x,y,z+1 clamped) )
// 2.56 MB — same footprint/locality as the source voxel, fully L2-resident.
__global__ __launch_bounds__(256) void pack_zpair_kernel(
    const float* __restrict__ v, __half2* __restrict__ zp)
{
    int idx = blockIdx.x * blockDim.x + threadIdx.x;
    if (idx >= N_CELLS) return;
    int z  = idx & 15;
    float a = v[idx];
    float b = (z < 15) ? v[idx + 1] : a;   // z=15 never used as interp base
    zp[idx] = __floats2half2_rn(a, b);
}

__global__ __launch_bounds__(256) void nerf_depth_kernel(
    const float* __restrict__ rays_o,
    const float* __restrict__ rays_d,
    const __half2* __restrict__ zp,
    float* __restrict__ depth_out,
    float stepf, float delta)
{
    const int lane = threadIdx.x & 63;
    const int sub  = lane & (GRP_W - 1);
    const int grp  = lane >> 4;
    const int wave = (blockIdx.x * blockDim.x + threadIdx.x) >> 6;
    const int ray  = wave * 4 + grp;         // 86400 = 4 * 21600, exact

    const float ox = rays_o[3*ray+0], oy = rays_o[3*ray+1], oz = rays_o[3*ray+2];
    const float dx = rays_d[3*ray+0], dy = rays_d[3*ray+1], dz = rays_d[3*ray+2];

    const float cx1 = 199.0f / 80.0f;                  const float cx0 = 40.0f * cx1;
    const float cz1 = 15.0f / (5.4f - (-1.0f));        const float cz0 = 1.0f * cz1;
    const float negdelta = -delta;

    float T = 1.0f;          // group-uniform running transmittance
    float depth_acc = 0.0f;  // per-lane partial depth
    bool  done = false;      // group-uniform

    for (int c = 0; c < N_CHUNK; ++c) {
        const int  s     = c * GRP_W + sub;
        const bool valid = (s < N_SAMP);
        const float z  = __fmul_rn(stepf, (float)s);
        // mask must stay bit-exact vs numpy: separate mul + add, strict compares
        const float px = __fadd_rn(ox, __fmul_rn(dx, z));
        const float py = __fadd_rn(oy, __fmul_rn(dy, z));
        const float pz = __fadd_rn(oz, __fmul_rn(dz, z));
        const bool inside = !((fmaxf(fabsf(px), fabsf(py)) > 40.0f) |
                              (pz < -1.0f) | (pz > 5.4f));
        const bool inb = (!done) && valid && inside;

        // group termination: ray starts inside a convex box, so an all-outside
        // chunk means outside forever
        const unsigned long long bal = __ballot(inb);
        if (((unsigned)(bal >> (grp * GRP_W)) & 0xFFFFu) == 0u) done = true;
        if (__all(done)) break;

        float alpha = 0.0f, az = 0.0f;
        if (inb) {
            float ix = fminf(fmaxf(__builtin_fmaf(px, cx1, cx0), 0.0f), 199.0f);
            float iy = fminf(fmaxf(__builtin_fmaf(py, cx1, cx0), 0.0f), 199.0f);
            float iz = fminf(fmaxf(__builtin_fmaf(pz, cz1, cz0), 0.0f), 15.0f);
            int x0 = min((int)ix, 198);
            int y0 = min((int)iy, 198);
            int z0 = min((int)iz, 14);
            float fx = ix - (float)x0;
            float fy = iy - (float)y0;
            float fz = iz - (float)z0;
            // 8 corners via 4 aligned dword loads of packed (v[z], v[z+1])
            const int cell = (x0 * 200 + y0) * 16 + z0;
            __half2 h00 = zp[cell];          // (x0,   y0  )
            __half2 h01 = zp[cell + 16];     // (x0,   y0+1)
            __half2 h10 = zp[cell + 3200];   // (x0+1, y0  )
            __half2 h11 = zp[cell + 3216];   // (x0+1, y0+1)
            float c00 = __low2float(h00) + fz * (__high2float(h00) - __low2float(h00));
            float c01 = __low2float(h01) + fz * (__high2float(h01) - __low2float(h01));
            float c10 = __low2float(h10) + fz * (__high2float(h10) - __low2float(h10));
            float c11 = __low2float(h11) + fz * (__high2float(h11) - __low2float(h11));
            float c0  = c00 + fy * (c01 - c00);
            float c1  = c10 + fy * (c11 - c10);
            float d   = c0  + fx * (c1  - c0);
            // alpha = 1 - exp(-delta*softplus(d)) = 1 - 2^(-delta*log2(1+e^d))
            float e2 = exp2f(d * LOG2E);
            float lg = __log2f(1.0f + e2);
            alpha = 1.0f - exp2f(negdelta * lg);
            az = alpha * z;
        }

        float g = fmaxf(1.0f - alpha, 1e-10f);

        // 16-lane inclusive prefix product via DPP row_shr
        float P = g;
        P *= ROW_SHR_OLD1(P, 1);
        P *= ROW_SHR_OLD1(P, 2);
        P *= ROW_SHR_OLD1(P, 4);
        P *= ROW_SHR_OLD1(P, 8);
        float E = ROW_SHR_OLD1(P, 1);      // exclusive prefix (lane0 -> 1.0)

        depth_acc = __builtin_fmaf(az, T * E, depth_acc);
        T *= SWZ(P, SWZ_BCAST15);          // chunk product -> all 16 lanes

        if (T < 1e-6f) done = true;        // residual depth <= 1e-6 * 57.4
    }

    // sum the 16 per-lane partials
    depth_acc += SWZ(depth_acc, SWZ_XOR(1));
    depth_acc += SWZ(depth_acc, SWZ_XOR(2));
    depth_acc += SWZ(depth_acc, SWZ_XOR(4));
    depth_acc += SWZ(depth_acc, SWZ_XOR(8));
    if (sub == 0) depth_out[ray] = depth_acc;
}

extern "C" void kernel_launch(void* const* d_in, const int* in_sizes, int n_in,
                              void* d_out, int out_size, void* d_ws, size_t ws_size,
                              hipStream_t stream) {
    (void)in_sizes; (void)n_in; (void)ws_size; (void)out_size;
    const float* rays_o = (const float*)d_in[0];
    const float* rays_d = (const float*)d_in[1];
    const float* voxel  = (const float*)d_in[2];
    float* out = (float*)d_out;
    __half2* zp = (__half2*)d_ws;   // 640000 * 4B = 2.56 MB

    // numpy constant chain in float32: step == 0.2f
    float rngz  = 5.4f - (-1.0f);
    float prod  = (80.0f * 80.0f) * rngz;
    float ratio = prod / 640000.0f;
    float stepf = (float)(0.5 * pow((double)ratio, 1.0 / 3.0));
    float delta = stepf * 286.0f - stepf * 285.0f;

    pack_zpair_kernel<<<(N_CELLS + 255) / 256, 256, 0, stream>>>(voxel, zp);
    // 4 rays/wave, 4 waves/block => 16 rays/block; 86400/16 = 5400 blocks
    nerf_depth_kernel<<<N_RAYS / 16, 256, 0, stream>>>(rays_o, rays_d, zp,
                                                       out, stepf, delta);
}

// Round 11
// 28.124 us; speedup vs baseline: 1.3838x; 1.1600x over previous
//
#include <hip/hip_runtime.h>
#include <math.h>

#define N_RAYS 86400
#define N_SAMP 287
#define GRP_W  16          // lanes per ray-group (4 groups per wave)
#define N_CHUNK 18         // ceil(287/16)
#define LOG2E 1.4426950408889634f
#define NBLK   2048        // 8 blocks/CU on 256 CUs — one resident generation
#define NGROUP (NBLK * 16) // 32768 concurrent ray-groups

// DPP row_shr:N prefix-shift within the 16-lane row; lanes below the row edge
// read `old` = 1.0f (multiplicative identity).
#define ROW_SHR_OLD1(x, N)                                                   \
    __int_as_float(__builtin_amdgcn_update_dpp(                              \
        0x3f800000 /*1.0f*/, __float_as_int(x), 0x110 | (N), 0xF, 0xF, false))

// ds_swizzle BitMode: new_lane = ((lane & and) | or) ^ xor  (per 32-lane half)
#define SWZ(x, pat) __int_as_float(__builtin_amdgcn_ds_swizzle(__float_as_int(x), (pat)))
#define SWZ_BCAST15 0x1F0   // lane 15 of each 16-group
#define SWZ_XOR(m)  (((m) << 10) | 0x1F)

__global__ __launch_bounds__(256) void nerf_depth_kernel(
    const float* __restrict__ rays_o,
    const float* __restrict__ rays_d,
    const float* __restrict__ voxel,
    float* __restrict__ depth_out,
    float stepf, float delta)
{
    const int lane = threadIdx.x & 63;
    const int sub  = lane & (GRP_W - 1);
    const int grp  = lane >> 4;
    const int gid  = (blockIdx.x * blockDim.x + threadIdx.x) >> 4;

    const float cx1 = 199.0f / 80.0f;                  const float cx0 = 40.0f * cx1;
    const float cz1 = 15.0f / (5.4f - (-1.0f));        const float cz0 = 1.0f * cz1;
    const float negdelta = -delta;

    // persistent: each group serially marches rays gid, gid+32768, ...
    for (int ray = gid; ray < N_RAYS; ray += NGROUP) {
        const float ox = rays_o[3*ray+0], oy = rays_o[3*ray+1], oz = rays_o[3*ray+2];
        const float dx = rays_d[3*ray+0], dy = rays_d[3*ray+1], dz = rays_d[3*ray+2];

        float T = 1.0f;          // group-uniform running transmittance
        float depth_acc = 0.0f;  // per-lane partial depth
        bool  done = false;      // group-uniform

        for (int c = 0; c < N_CHUNK; ++c) {
            const int  s     = c * GRP_W + sub;
            const bool valid = (s < N_SAMP);
            const float z  = __fmul_rn(stepf, (float)s);
            // mask must stay bit-exact vs numpy: separate mul+add, strict cmps
            const float px = __fadd_rn(ox, __fmul_rn(dx, z));
            const float py = __fadd_rn(oy, __fmul_rn(dy, z));
            const float pz = __fadd_rn(oz, __fmul_rn(dz, z));
            const bool inside = !((fmaxf(fabsf(px), fabsf(py)) > 40.0f) |
                                  (pz < -1.0f) | (pz > 5.4f));
            const bool inb = (!done) && valid && inside;

            // group termination: ray starts inside a convex box, so an
            // all-outside chunk means outside forever
            const unsigned long long bal = __ballot(inb);
            if (((unsigned)(bal >> (grp * GRP_W)) & 0xFFFFu) == 0u) done = true;
            if (__all(done)) break;

            float alpha = 0.0f, az = 0.0f;
            if (inb) {
                float ix = fminf(fmaxf(__builtin_fmaf(px, cx1, cx0), 0.0f), 199.0f);
                float iy = fminf(fmaxf(__builtin_fmaf(py, cx1, cx0), 0.0f), 199.0f);
                float iz = fminf(fmaxf(__builtin_fmaf(pz, cz1, cz0), 0.0f), 15.0f);
                int x0 = min((int)ix, 198);
                int y0 = min((int)iy, 198);
                int z0 = min((int)iz, 14);
                float fx = ix - (float)x0;
                float fy = iy - (float)y0;
                float fz = iz - (float)z0;
                const float* p00 = voxel + ((x0 * 200 + y0) * 16 + z0);
                float c000 = p00[0],    c001 = p00[1];
                float c010 = p00[16],   c011 = p00[17];
                float c100 = p00[3200], c101 = p00[3201];
                float c110 = p00[3216], c111 = p00[3217];
                float c00 = c000 + fz * (c001 - c000);
                float c01 = c010 + fz * (c011 - c010);
                float c10 = c100 + fz * (c101 - c100);
                float c11 = c110 + fz * (c111 - c110);
                float c0  = c00 + fy * (c01 - c00);
                float c1  = c10 + fy * (c11 - c10);
                float d   = c0  + fx * (c1  - c0);
                // alpha = 1 - exp(-delta*softplus(d)) = 1 - 2^(-delta*log2(1+e^d))
                float e2 = exp2f(d * LOG2E);
                float lg = __log2f(1.0f + e2);
                alpha = 1.0f - exp2f(negdelta * lg);
                az = alpha * z;
            }

            float g = fmaxf(1.0f - alpha, 1e-10f);

            // 16-lane inclusive prefix product via DPP row_shr
            float P = g;
            P *= ROW_SHR_OLD1(P, 1);
            P *= ROW_SHR_OLD1(P, 2);
            P *= ROW_SHR_OLD1(P, 4);
            P *= ROW_SHR_OLD1(P, 8);
            float E = ROW_SHR_OLD1(P, 1);  // exclusive prefix (lane0 -> 1.0)

            depth_acc = __builtin_fmaf(az, T * E, depth_acc);
            T *= SWZ(P, SWZ_BCAST15);      // chunk product -> all 16 lanes

            if (T < 1e-6f) done = true;    // residual depth <= 1e-6 * 57.4
        }

        // sum the 16 per-lane partials
        depth_acc += SWZ(depth_acc, SWZ_XOR(1));
        depth_acc += SWZ(depth_acc, SWZ_XOR(2));
        depth_acc += SWZ(depth_acc, SWZ_XOR(4));
        depth_acc += SWZ(depth_acc, SWZ_XOR(8));
        if (sub == 0) depth_out[ray] = depth_acc;
    }
}

extern "C" void kernel_launch(void* const* d_in, const int* in_sizes, int n_in,
                              void* d_out, int out_size, void* d_ws, size_t ws_size,
                              hipStream_t stream) {
    (void)in_sizes; (void)n_in; (void)d_ws; (void)ws_size; (void)out_size;
    const float* rays_o = (const float*)d_in[0];
    const float* rays_d = (const float*)d_in[1];
    const float* voxel  = (const float*)d_in[2];
    float* out = (float*)d_out;

    // numpy constant chain in float32: step == 0.2f
    float rngz  = 5.4f - (-1.0f);
    float prod  = (80.0f * 80.0f) * rngz;
    float ratio = prod / 640000.0f;
    float stepf = (float)(0.5 * pow((double)ratio, 1.0 / 3.0));
    float delta = stepf * 286.0f - stepf * 285.0f;

    // persistent grid: 2048 blocks = 8 per CU, each group strides ray space
    nerf_depth_kernel<<<NBLK, 256, 0, stream>>>(rays_o, rays_d, voxel,
                                                out, stepf, delta);
}